// Round 4
// baseline (178.431 us; speedup 1.0000x reference)
//
#include <hip/hip_runtime.h>

#define DIOU_EPS 1e-7f

constexpr int BLOCK = 256;               // 4 waves
constexpr int ITEMS = 4;                 // elements per thread
constexpr int CHUNK = BLOCK * ITEMS;     // 1024 elements per block

// LDS tile: A 16KB + B 16KB + M 4KB = 36KB -> 4 blocks/CU resident
constexpr int A_CHUNKS = CHUNK * 16 / 1024;   // 16 x 1KB
constexpr int B_CHUNKS = CHUNK * 16 / 1024;   // 16 x 1KB
constexpr int M_CHUNKS = CHUNK * 4 / 1024;    // 4 x 1KB
constexpr int N_CHUNKS = A_CHUNKS + B_CHUNKS + M_CHUNKS;  // 36
constexpr int CHUNKS_PER_WAVE = N_CHUNKS / 4;             // 9

#define GLOBAL_TO_LDS16(g, l)                                                  \
    __builtin_amdgcn_global_load_lds(                                          \
        (const __attribute__((address_space(1))) void*)(g),                    \
        (__attribute__((address_space(3))) void*)(l), 16, 0, 0)

__global__ void zero_out_kernel(float* out) {
    out[0] = 0.0f;
}

__device__ __forceinline__ float rcp_fast(float x) {
    return __builtin_amdgcn_rcpf(x);     // v_rcp_f32 ~1ulp; abs threshold 3.8e-2 -> safe
}

__device__ __forceinline__ float diou_elem(float4 a, float4 b, int m) {
    float a1 = (a.z - a.x) * (a.w - a.y);
    float a2 = (b.z - b.x) * (b.w - b.y);

    float iw = fmaxf(fminf(a.z, b.z) - fmaxf(a.x, b.x), 0.0f);
    float ih = fmaxf(fminf(a.w, b.w) - fmaxf(a.y, b.y), 0.0f);
    float inter = iw * ih;
    float uni = a1 + a2 - inter;

    float wc = fmaxf(a.z, b.z) - fminf(a.x, b.x);
    float hc = fmaxf(a.w, b.w) - fminf(a.y, b.y);
    float area_c = wc * hc;

    float dx = (a.x + a.z - b.x - b.z) * 0.5f;
    float dy = (a.y + a.w - b.y - b.w) * 0.5f;
    float d2 = dx * dx + dy * dy;
    float diag2 = wc * wc + hc * hc;

    // loss = 1 - diou = 2 - inter/uni - uni/area_c + d2/(diag2+eps)
    float loss = 2.0f - inter * rcp_fast(uni)
                      - uni   * rcp_fast(area_c)
                      + d2    * rcp_fast(diag2 + DIOU_EPS);

    return (m != 0) ? loss : 0.0f;
}

__global__ __launch_bounds__(BLOCK) void diou_loss_kernel(
    const float4* __restrict__ boxes1,
    const float4* __restrict__ boxes2,
    const int* __restrict__ mask,
    const int* __restrict__ num_boxes,
    float* __restrict__ out,
    int n)
{
    __shared__ float4 Alds[CHUNK];   // 16 KB
    __shared__ float4 Blds[CHUNK];   // 16 KB
    __shared__ int    Mlds[CHUNK];   //  4 KB
    __shared__ float  wave_sums[BLOCK / 64];

    const int t    = threadIdx.x;
    const int lane = t & 63;
    const int wave = t >> 6;
    const long long base = (long long)blockIdx.x * CHUNK;

    float acc = 0.0f;

    if (base + CHUNK <= n) {
        // ---- async DMA staging: 36 x 1KB chunks, 9 per wave, zero VGPR cost,
        // all outstanding until the single barrier drain ----
        const char* Ag = (const char*)(boxes1 + base);
        const char* Bg = (const char*)(boxes2 + base);
        const char* Mg = (const char*)(mask + base);
        char* Al = (char*)&Alds[0];
        char* Bl = (char*)&Blds[0];
        char* Ml = (char*)&Mlds[0];

        #pragma unroll
        for (int k = 0; k < CHUNKS_PER_WAVE; ++k) {
            int c = wave * CHUNKS_PER_WAVE + k;   // wave-uniform
            const char* g;
            char* l;
            if (c < A_CHUNKS) {
                g = Ag + c * 1024;
                l = Al + c * 1024;
            } else if (c < A_CHUNKS + B_CHUNKS) {
                int cc = c - A_CHUNKS;
                g = Bg + cc * 1024;
                l = Bl + cc * 1024;
            } else {
                int cc = c - A_CHUNKS - B_CHUNKS;
                g = Mg + cc * 1024;
                l = Ml + cc * 1024;
            }
            GLOBAL_TO_LDS16(g + lane * 16, l);    // LDS dst = l + lane*16 (implicit)
        }
        __syncthreads();                          // drains vmcnt, publishes LDS

        // ---- compute from LDS: ds_read_b128, consecutive lanes x 16B -> conflict-free
        #pragma unroll
        for (int j = 0; j < ITEMS; ++j) {
            int e = j * BLOCK + t;
            acc += diou_elem(Alds[e], Blds[e], Mlds[e]);
        }
    } else {
        // tail path (unused for n = 4,194,304, kept for generality)
        for (int j = 0; j < ITEMS; ++j) {
            long long i = base + j * BLOCK + t;
            if (i < n) acc += diou_elem(boxes1[i], boxes2[i], mask[i]);
        }
        __syncthreads();
    }

    // wave-64 reduce
    #pragma unroll
    for (int off = 32; off > 0; off >>= 1)
        acc += __shfl_down(acc, off, 64);

    if (lane == 0) wave_sums[wave] = acc;
    __syncthreads();

    if (t == 0) {
        float s = wave_sums[0] + wave_sums[1] + wave_sums[2] + wave_sums[3];
        float inv_nb = 1.0f / (float)num_boxes[0];
        atomicAdd(out, s * inv_nb);
    }
}

extern "C" void kernel_launch(void* const* d_in, const int* in_sizes, int n_in,
                              void* d_out, int out_size, void* d_ws, size_t ws_size,
                              hipStream_t stream) {
    const float4* boxes1 = (const float4*)d_in[0];   // (B,Q,4) f32
    const float4* boxes2 = (const float4*)d_in[1];   // (B,Q,4) f32
    const int* mask = (const int*)d_in[2];           // (B,Q) bool -> int32
    const int* num_boxes = (const int*)d_in[3];      // scalar

    float* out = (float*)d_out;
    int n = in_sizes[2];                             // B*Q pairs

    zero_out_kernel<<<1, 1, 0, stream>>>(out);

    int grid = (n + CHUNK - 1) / CHUNK;              // 4096 for n = 4,194,304
    diou_loss_kernel<<<grid, BLOCK, 0, stream>>>(boxes1, boxes2, mask, num_boxes, out, n);
}

// Round 5
// 163.215 us; speedup vs baseline: 1.0932x; 1.0932x over previous
//
#include <hip/hip_runtime.h>

#define DIOU_EPS 1e-7f

constexpr int BLOCK = 256;              // 4 waves
constexpr int GRID  = 1024;             // 4 blocks/CU — fully persistent
constexpr int VPT   = 4;                // consecutive elements per thread per tile
constexpr int TILE  = BLOCK * VPT;      // 1024 elements per block-tile

__device__ __forceinline__ float rcp_fast(float x) {
    return __builtin_amdgcn_rcpf(x);    // v_rcp_f32 ~1ulp; abs threshold 3.8e-2 -> safe
}

__device__ __forceinline__ float diou_elem(float4 a, float4 b, int m) {
    float a1 = (a.z - a.x) * (a.w - a.y);
    float a2 = (b.z - b.x) * (b.w - b.y);

    float iw = fmaxf(fminf(a.z, b.z) - fmaxf(a.x, b.x), 0.0f);
    float ih = fmaxf(fminf(a.w, b.w) - fmaxf(a.y, b.y), 0.0f);
    float inter = iw * ih;
    float uni = a1 + a2 - inter;

    float wc = fmaxf(a.z, b.z) - fminf(a.x, b.x);
    float hc = fmaxf(a.w, b.w) - fminf(a.y, b.y);
    float area_c = wc * hc;

    float dx = (a.x + a.z - b.x - b.z) * 0.5f;
    float dy = (a.y + a.w - b.y - b.w) * 0.5f;
    float d2 = dx * dx + dy * dy;
    float diag2 = wc * wc + hc * hc;

    // loss = 1 - diou = 2 - inter/uni - uni/area_c + d2/(diag2+eps)
    float loss = 2.0f - inter * rcp_fast(uni)
                      - uni   * rcp_fast(area_c)
                      + d2    * rcp_fast(diag2 + DIOU_EPS);

    return (m != 0) ? loss : 0.0f;
}

struct Tile {
    float4 A[VPT];
    float4 B[VPT];
    int4   M;
};

__device__ __forceinline__ void load_tile(const float4* __restrict__ boxes1,
                                          const float4* __restrict__ boxes2,
                                          const int4* __restrict__ mask4,
                                          long long e0, Tile& T) {
    // thread owns 4 CONSECUTIVE elements starting at e0:
    //   4x dwordx4 A (imm offsets 0/16/32/48), 4x dwordx4 B, 1x dwordx4 mask
    #pragma unroll
    for (int j = 0; j < VPT; ++j) T.A[j] = boxes1[e0 + j];
    #pragma unroll
    for (int j = 0; j < VPT; ++j) T.B[j] = boxes2[e0 + j];
    T.M = mask4[e0 >> 2];
}

__global__ __launch_bounds__(BLOCK, 4) void diou_partial_kernel(
    const float4* __restrict__ boxes1,
    const float4* __restrict__ boxes2,
    const int* __restrict__ mask,
    float* __restrict__ ws,
    int n)
{
    const int t = threadIdx.x;
    const int4* mask4 = (const int4*)mask;
    const long long nfull = n / TILE;

    float acc = 0.0f;

    // ---- software-pipelined persistent loop: load tile k+1 while computing tile k ----
    Tile cur, nxt;
    long long tb = blockIdx.x;
    bool any = tb < nfull;
    if (any) load_tile(boxes1, boxes2, mask4, tb * TILE + (long long)t * VPT, cur);

    while (any) {
        long long tn = tb + GRID;
        bool hn = tn < nfull;
        if (hn) load_tile(boxes1, boxes2, mask4, tn * TILE + (long long)t * VPT, nxt);

        // compute current tile while next tile's 9 loads are in flight
        int mm[VPT] = {cur.M.x, cur.M.y, cur.M.z, cur.M.w};
        #pragma unroll
        for (int j = 0; j < VPT; ++j) acc += diou_elem(cur.A[j], cur.B[j], mm[j]);

        cur = nxt;      // register rename — copy-propagated, no real movs
        tb = tn;
        any = hn;
    }

    // tail (empty for n = 4,194,304; kept for generality)
    for (long long i = nfull * TILE + (long long)blockIdx.x * BLOCK + t; i < n;
         i += (long long)GRID * BLOCK)
        acc += diou_elem(boxes1[i], boxes2[i], mask[i]);

    // block reduce -> one partial per block, NO global atomics
    #pragma unroll
    for (int off = 32; off > 0; off >>= 1)
        acc += __shfl_down(acc, off, 64);

    __shared__ float wsum[BLOCK / 64];
    if ((t & 63) == 0) wsum[t >> 6] = acc;
    __syncthreads();
    if (t == 0) ws[blockIdx.x] = wsum[0] + wsum[1] + wsum[2] + wsum[3];
}

__global__ __launch_bounds__(BLOCK) void finalize_kernel(
    const float* __restrict__ ws,
    const int* __restrict__ num_boxes,
    float* __restrict__ out)
{
    const int t = threadIdx.x;
    float a = 0.0f;
    #pragma unroll
    for (int i = 0; i < GRID / BLOCK; ++i) a += ws[i * BLOCK + t];

    #pragma unroll
    for (int off = 32; off > 0; off >>= 1)
        a += __shfl_down(a, off, 64);

    __shared__ float wsum[BLOCK / 64];
    if ((t & 63) == 0) wsum[t >> 6] = a;
    __syncthreads();
    if (t == 0)
        out[0] = (wsum[0] + wsum[1] + wsum[2] + wsum[3]) / (float)num_boxes[0];
}

extern "C" void kernel_launch(void* const* d_in, const int* in_sizes, int n_in,
                              void* d_out, int out_size, void* d_ws, size_t ws_size,
                              hipStream_t stream) {
    const float4* boxes1 = (const float4*)d_in[0];   // (B,Q,4) f32
    const float4* boxes2 = (const float4*)d_in[1];   // (B,Q,4) f32
    const int* mask = (const int*)d_in[2];           // (B,Q) bool -> int32
    const int* num_boxes = (const int*)d_in[3];      // scalar

    float* out = (float*)d_out;
    float* partials = (float*)d_ws;                  // GRID floats of scratch
    int n = in_sizes[2];                             // B*Q pairs

    diou_partial_kernel<<<GRID, BLOCK, 0, stream>>>(boxes1, boxes2, mask, partials, n);
    finalize_kernel<<<1, BLOCK, 0, stream>>>(partials, num_boxes, out);
}